// Round 2
// baseline (938.602 us; speedup 1.0000x reference)
//
#include <hip/hip_runtime.h>
#include <cstdint>

#define TOKENS 16384
#define IN_F   4096
#define OUT_F  4096

typedef int v4i __attribute__((ext_vector_type(4)));

// --- async global->LDS, 16B per lane (dest = wave-uniform base + lane*16) ---
__device__ __forceinline__ void async_lds16(const void* g, const void* l) {
    __builtin_amdgcn_global_load_lds(
        (const __attribute__((address_space(1))) void*)(uintptr_t)g,
        (__attribute__((address_space(3))) void*)(uint32_t)(uintptr_t)l,
        16, 0, 0);
}

// ---------------------------------------------------------------------------
// Kernel 1: per-token dynamic int8 quant of x. One block (256 thr) per row.
// ---------------------------------------------------------------------------
__global__ __launch_bounds__(256) void act_quant_kernel(
        const float* __restrict__ x,
        signed char* __restrict__ qx,
        float* __restrict__ act_scale) {
    const int row = blockIdx.x;
    const int tid = threadIdx.x;
    const float4* xr = (const float4*)(x + (size_t)row * IN_F);

    float4 v[4];
    float m = 0.f;
#pragma unroll
    for (int i = 0; i < 4; ++i) {
        v[i] = xr[i * 256 + tid];
        m = fmaxf(m, fmaxf(fmaxf(fabsf(v[i].x), fabsf(v[i].y)),
                           fmaxf(fabsf(v[i].z), fabsf(v[i].w))));
    }
#pragma unroll
    for (int off = 32; off > 0; off >>= 1)
        m = fmaxf(m, __shfl_xor(m, off, 64));
    __shared__ float wmax[4];
    if ((tid & 63) == 0) wmax[tid >> 6] = m;
    __syncthreads();
    m = fmaxf(fmaxf(wmax[0], wmax[1]), fmaxf(wmax[2], wmax[3]));

    const float inv = (m == 0.f) ? 0.f : 127.0f / m;
    if (tid == 0) act_scale[row] = (m == 0.f) ? 1.0f : m / 127.0f;

    int* qr = (int*)(qx + (size_t)row * IN_F);
#pragma unroll
    for (int i = 0; i < 4; ++i) {
        int q0 = (int)fminf(fmaxf(rintf(v[i].x * inv), -128.f), 127.f);
        int q1 = (int)fminf(fmaxf(rintf(v[i].y * inv), -128.f), 127.f);
        int q2 = (int)fminf(fmaxf(rintf(v[i].z * inv), -128.f), 127.f);
        int q3 = (int)fminf(fmaxf(rintf(v[i].w * inv), -128.f), 127.f);
        qr[i * 256 + tid] = (q0 & 255) | ((q1 & 255) << 8) |
                            ((q2 & 255) << 16) | ((q3 & 255) << 24);
    }
}

// ---------------------------------------------------------------------------
// Kernel 2: unpack int4 nibbles -> int8 [OUT_F][IN_F].
// ---------------------------------------------------------------------------
__global__ __launch_bounds__(256) void unpack_w_kernel(
        const int* __restrict__ qw,
        signed char* __restrict__ w8) {
    const size_t idx = ((size_t)blockIdx.x * 256 + threadIdx.x) * 4;
    const int4 q = *(const int4*)(qw + idx);
    const int b0 = ((((q.x >> 4) & 15) - 8) & 255);
    const int b1 = (((q.x & 15) - 8) & 255);
    const int b2 = ((((q.y >> 4) & 15) - 8) & 255);
    const int b3 = (((q.y & 15) - 8) & 255);
    const int b4 = ((((q.z >> 4) & 15) - 8) & 255);
    const int b5 = (((q.z & 15) - 8) & 255);
    const int b6 = ((((q.w >> 4) & 15) - 8) & 255);
    const int b7 = (((q.w & 15) - 8) & 255);
    int2 d;
    d.x = b0 | (b1 << 8) | (b2 << 16) | (b3 << 24);
    d.y = b4 | (b5 << 8) | (b6 << 16) | (b7 << 24);
    *(int2*)(w8 + idx * 2) = d;
}

// ---------------------------------------------------------------------------
// Kernel 3: int8 GEMM. BM=128, BN=128, BK=64. 256 thr = 4 waves (2x2),
// wave tile 64x64 = 4x4 grid of v_mfma_i32_16x16x64_i8.
//
// R2 change: acc halved 128->64 AGPRs (wave tile 64x128 -> 64x64) to lift
// occupancy from 2 waves/SIMD to 4 (launch_bounds(256,4), LDS 32KB/block ->
// 4 blocks/CU). R1 showed the kernel is latency-bound (MfmaUtil 28%, HBM 10%,
// occupancy 22%) and software pipelining alone was neutral -- the wave pool,
// not the schedule, was the limiter.
//
// LDS layout is FRAGMENT-ORDER (zero bank conflicts, global_load_lds
// compatible), double-buffered, counted-vmcnt pipeline:
//   iter t: issue stage of tile t+1 (4 global_load_lds) -> s_waitcnt vmcnt(4)
//           (tile t landed, t+1 stays in flight) -> raw barrier -> compute ->
//           raw barrier.
// ---------------------------------------------------------------------------
__global__ __launch_bounds__(256, 4) void gemm_i8_kernel(
        const signed char* __restrict__ qx,
        const signed char* __restrict__ w8,
        const float* __restrict__ act_scale,
        const float* __restrict__ wscale,
        const float* __restrict__ bias,
        float* __restrict__ out) {
    __shared__ __align__(16) signed char sA[2][128 * 64];   // 2 x 8 KiB
    __shared__ __align__(16) signed char sB[2][128 * 64];   // 2 x 8 KiB

    const int nt = blockIdx.x & 31;       // OUT_F/128 = 32 n-tiles
    const int mt = blockIdx.x >> 5;       // TOKENS/128 = 128 m-tiles
    const int m0 = mt * 128, n0 = nt * 128;
    const int tid  = threadIdx.x;
    const int lane = tid & 63;
    const int wave = tid >> 6;
    const int wm = (wave >> 1) * 64;      // wave row offset (0 or 64)
    const int wn = (wave & 1) * 64;       // wave col offset (0 or 64)

    // staging: wave w fills A-groups {2w,2w+1} and B-groups {2w,2w+1}.
    // lane's global element for group g: row = 16g + (lane&15), k = (lane>>4)*16
    const int lrow = lane & 15;
    const int lcol = (lane >> 4) * 16;
    const signed char* gA0 = qx + (size_t)(m0 + 16 * (2 * wave) + lrow) * IN_F + lcol;
    const signed char* gA1 = gA0 + 16 * IN_F;
    const signed char* gB0 = w8 + (size_t)(n0 + 16 * (2 * wave) + lrow) * IN_F + lcol;
    const signed char* gB1 = gB0 + 16 * IN_F;
    const int goff = (2 * wave) * 1024;   // wave's group base within a buffer

    v4i acc[4][4];
#pragma unroll
    for (int i = 0; i < 4; ++i)
#pragma unroll
        for (int j = 0; j < 4; ++j) acc[i][j] = (v4i){0, 0, 0, 0};

    auto STAGE = [&](int buf, int k0) {
        signed char* a = sA[buf] + goff;
        signed char* b = sB[buf] + goff;
        async_lds16(gA0 + k0, a);
        async_lds16(gA1 + k0, a + 1024);
        async_lds16(gB0 + k0, b);
        async_lds16(gB1 + k0, b + 1024);
    };

    auto COMPUTE = [&](int buf) {
        const signed char* fA = sA[buf] + (wm >> 4) * 1024 + lane * 16;
        const signed char* fB = sB[buf] + (wn >> 4) * 1024 + lane * 16;
        v4i af[4], bf[4];
#pragma unroll
        for (int i = 0; i < 4; ++i)
            af[i] = *(const v4i*)(fA + i * 1024);
#pragma unroll
        for (int j = 0; j < 4; ++j)
            bf[j] = *(const v4i*)(fB + j * 1024);
#pragma unroll
        for (int i = 0; i < 4; ++i)
#pragma unroll
            for (int j = 0; j < 4; ++j)
                acc[i][j] = __builtin_amdgcn_mfma_i32_16x16x64_i8(
                    af[i], bf[j], acc[i][j], 0, 0, 0);
    };

    // ---- software pipeline ----
    STAGE(0, 0);
    int cur = 0;
    for (int k0 = 0; k0 < IN_F - 64; k0 += 64) {
        STAGE(cur ^ 1, k0 + 64);                        // next tile in flight
        asm volatile("s_waitcnt vmcnt(4)" ::: "memory"); // cur's 4 loads landed
        __builtin_amdgcn_s_barrier();                   // all waves' cur visible
        __builtin_amdgcn_sched_barrier(0);              // pin ds_reads after bar
        COMPUTE(cur);
        __builtin_amdgcn_sched_barrier(0);              // pin ds_reads before bar
        __builtin_amdgcn_s_barrier();                   // reads done -> safe to
        cur ^= 1;                                       //   overwrite next iter
    }
    asm volatile("s_waitcnt vmcnt(0)" ::: "memory");
    __builtin_amdgcn_s_barrier();
    __builtin_amdgcn_sched_barrier(0);
    COMPUTE(cur);

    // epilogue: out[m][n] = acc * act_scale[m]*wscale[n] + bias[n]
    // C/D mapping: col = lane&15, row = (lane>>4)*4 + reg
    const int col_lane = lane & 15;
    const int row_q    = (lane >> 4) * 4;
    float4 as4[4];
#pragma unroll
    for (int i = 0; i < 4; ++i)
        as4[i] = *(const float4*)(act_scale + m0 + wm + i * 16 + row_q);

#pragma unroll
    for (int j = 0; j < 4; ++j) {
        const int n = n0 + wn + j * 16 + col_lane;
        const float wsn = wscale[n];
        const float bn  = bias[n];
#pragma unroll
        for (int i = 0; i < 4; ++i) {
            const int mb = m0 + wm + i * 16 + row_q;
            float* orow = out + (size_t)mb * OUT_F + n;
            const float* asp = (const float*)&as4[i];
#pragma unroll
            for (int r = 0; r < 4; ++r)
                orow[(size_t)r * OUT_F] = (float)acc[i][j][r] * (asp[r] * wsn) + bn;
        }
    }
}

// ---------------------------------------------------------------------------
extern "C" void kernel_launch(void* const* d_in, const int* in_sizes, int n_in,
                              void* d_out, int out_size, void* d_ws, size_t ws_size,
                              hipStream_t stream) {
    const float* x    = (const float*)d_in[0];
    const int*   qw   = (const int*)d_in[1];
    const float* wsc  = (const float*)d_in[2];
    const float* bias = (const float*)d_in[3];
    float* out = (float*)d_out;

    char* ws = (char*)d_ws;
    float*       act_scale = (float*)ws;
    signed char* qx        = (signed char*)(ws + 65536);
    signed char* w8        = (signed char*)(ws + 65536 + (size_t)TOKENS * IN_F);

    act_quant_kernel<<<TOKENS, 256, 0, stream>>>(x, qx, act_scale);
    unpack_w_kernel<<<(OUT_F * (IN_F / 2) / 4) / 256, 256, 0, stream>>>(qw, w8);
    gemm_i8_kernel<<<(TOKENS / 128) * (OUT_F / 128), 256, 0, stream>>>(
        qx, w8, act_scale, wsc, bias, out);
}

// Round 4
// 858.793 us; speedup vs baseline: 1.0929x; 1.0929x over previous
//
#include <hip/hip_runtime.h>
#include <cstdint>

#define TOKENS 16384
#define IN_F   4096
#define OUT_F  4096

typedef int v4i __attribute__((ext_vector_type(4)));
typedef int v2i __attribute__((ext_vector_type(2)));

// --- async global->LDS, 16B per lane (dest = wave-uniform base + lane*16) ---
__device__ __forceinline__ void async_lds16(const void* g, const void* l) {
    __builtin_amdgcn_global_load_lds(
        (const __attribute__((address_space(1))) void*)(uintptr_t)g,
        (__attribute__((address_space(3))) void*)(uint32_t)(uintptr_t)l,
        16, 0, 0);
}

// ---------------------------------------------------------------------------
// Kernel 1: per-token dynamic int8 quant of x. One block (256 thr) per row.
// qx is written in PERMUTED order: within each 16-col chunk, bytes are
// [cols 1,3,5,7 | 9,11,13,15 | 0,2,4,6 | 8,10,12,14]. The GEMM applies the
// same permutation to B (cheap nibble expand), so dot products are unchanged.
// Also emits rowsum[row] = sum_k q_x (int32) for the zero-point correction.
// ---------------------------------------------------------------------------
__global__ __launch_bounds__(256) void act_quant_kernel(
        const float* __restrict__ x,
        signed char* __restrict__ qx,
        float* __restrict__ act_scale,
        int* __restrict__ rowsum) {
    const int row = blockIdx.x;
    const int tid = threadIdx.x;
    const float4* xr = (const float4*)(x + (size_t)row * IN_F);

    float4 v[4];
    float m = 0.f;
#pragma unroll
    for (int i = 0; i < 4; ++i) {
        v[i] = xr[i * 256 + tid];
        m = fmaxf(m, fmaxf(fmaxf(fabsf(v[i].x), fabsf(v[i].y)),
                           fmaxf(fabsf(v[i].z), fabsf(v[i].w))));
    }
#pragma unroll
    for (int off = 32; off > 0; off >>= 1)
        m = fmaxf(m, __shfl_xor(m, off, 64));
    __shared__ float wmax[4];
    __shared__ int   wsum[4];
    if ((tid & 63) == 0) wmax[tid >> 6] = m;
    __syncthreads();
    m = fmaxf(fmaxf(wmax[0], wmax[1]), fmaxf(wmax[2], wmax[3]));

    const float inv = (m == 0.f) ? 0.f : 127.0f / m;
    if (tid == 0) act_scale[row] = (m == 0.f) ? 1.0f : m / 127.0f;

    unsigned* qr = (unsigned*)(qx + (size_t)row * IN_F);
    const int s = tid & 3;
    // dword position within the 16B chunk for this thread's perm output
    const int dwpos = (s == 0) ? 0 : (s == 1) ? 2 : (s == 2) ? 1 : 3;
    int lane_sum = 0;
#pragma unroll
    for (int i = 0; i < 4; ++i) {
        int q0 = (int)fminf(fmaxf(rintf(v[i].x * inv), -128.f), 127.f);
        int q1 = (int)fminf(fmaxf(rintf(v[i].y * inv), -128.f), 127.f);
        int q2 = (int)fminf(fmaxf(rintf(v[i].z * inv), -128.f), 127.f);
        int q3 = (int)fminf(fmaxf(rintf(v[i].w * inv), -128.f), 127.f);
        lane_sum += q0 + q1 + q2 + q3;
        unsigned D = (q0 & 255) | ((q1 & 255) << 8) |
                     ((q2 & 255) << 16) | ((q3 & 255) << 24);
        unsigned P = (unsigned)__shfl_xor((int)D, 1, 64);
        // even s: [b1(D),b3(D),b1(P),b3(P)] (odd cols); odd s: even cols
        unsigned Mo = ((s & 1) == 0)
                    ? __builtin_amdgcn_perm(P, D, 0x07050301u)
                    : __builtin_amdgcn_perm(D, P, 0x06040200u);
        qr[i * 256 + (tid >> 2) * 4 + dwpos] = Mo;
    }
#pragma unroll
    for (int off = 32; off > 0; off >>= 1)
        lane_sum += __shfl_xor(lane_sum, off, 64);
    if ((tid & 63) == 0) wsum[tid >> 6] = lane_sum;
    __syncthreads();
    if (tid == 0) rowsum[row] = wsum[0] + wsum[1] + wsum[2] + wsum[3];
}

// ---------------------------------------------------------------------------
// Kernel 2: narrow qweight int32 -> byte stream (no nibble work; 8 MB out).
// ---------------------------------------------------------------------------
__global__ __launch_bounds__(256) void repack_w_kernel(
        const int* __restrict__ qw,
        unsigned char* __restrict__ w4) {
    const size_t idx = ((size_t)blockIdx.x * 256 + threadIdx.x) * 16;
    const int4 a = *(const int4*)(qw + idx);
    const int4 b = *(const int4*)(qw + idx + 4);
    const int4 c = *(const int4*)(qw + idx + 8);
    const int4 d = *(const int4*)(qw + idx + 12);
    int4 o;
    o.x = (a.x & 255) | ((a.y & 255) << 8) | ((a.z & 255) << 16) | (a.w << 24);
    o.y = (b.x & 255) | ((b.y & 255) << 8) | ((b.z & 255) << 16) | (b.w << 24);
    o.z = (c.x & 255) | ((c.y & 255) << 8) | ((c.z & 255) << 16) | (c.w << 24);
    o.w = (d.x & 255) | ((d.y & 255) << 8) | ((d.z & 255) << 16) | (d.w << 24);
    *(int4*)(w4 + idx) = o;
}

// ---------------------------------------------------------------------------
// Kernel 3: int8 GEMM. BM=128, BN=256, BK=64. 256 thr = 4 waves (2x2),
// wave tile 64x128 = 4x8 of v_mfma_i32_16x16x64_i8.
//
// R3: LDS-pipe pressure (the R2 finding) cut ~2.4x:
//  - A fragments stream global->VGPR (no LDS at all), prefetched 1 K-step
//    ahead into ping-pong afA/afB.
//  - B staged in LDS PACKED (int4 nibbles, 8KB/step, double-buffered),
//    expanded in-register to biased nibbles [0,15]; the -8 bias is folded
//    into the epilogue via rowsum (acc_true = acc - 8*rowsum[m]); the
//    nibble lo/hi split is absorbed by the qx k-permutation (see kernel 1).
// B LDS layout: group g = 16 n-rows, 512B: (row r, kchunk16 kc) 8B at
//   g*512 + r*16 + (kc>>1)*256 + (kc&1)*8.  <=2-way bank aliasing (free).
// ---------------------------------------------------------------------------
__global__ __launch_bounds__(256, 2) void gemm_i8_kernel(
        const signed char* __restrict__ qx,
        const unsigned char* __restrict__ w4,
        const float* __restrict__ act_scale,
        const int* __restrict__ rowsum,
        const float* __restrict__ wscale,
        const float* __restrict__ bias,
        float* __restrict__ out) {
    __shared__ __align__(16) unsigned char sB[2][8192];  // packed B, 2 bufs

    const int nt = blockIdx.x & 15;       // OUT_F/256 = 16 n-tiles (fastest:
    const int mt = blockIdx.x >> 4;       //   consecutive blocks share A panel)
    const int m0 = mt * 128, n0 = nt * 256;
    const int tid  = threadIdx.x;
    const int lane = tid & 63;
    const int wave = tid >> 6;
    const int wm = (wave >> 1) * 64;      // wave row offset (0 or 64)
    const int wn = (wave & 1) * 128;      // wave col offset (0 or 128)
    const int lrow = lane & 15;
    const int kc   = lane >> 4;           // k-chunk 0..3

    // A fragment base: lane reads 16B at (m0+wm+16i+lrow)*IN_F + kc*16 + k0
    const signed char* aBase = qx + (size_t)(m0 + wm + lrow) * IN_F + kc * 16;

    // B staging: wave w issues 2 gld_lds, instr i=2w+u covers 32 rows:
    //   lane l: row = n0 + 32*i + 16*(l>>5) + (l&15),
    //           src byte = row*2048 + k0/2 + ((l>>4)&1)*16
    const unsigned char* bBase = w4 +
        (size_t)(n0 + 64 * wave + 16 * (lane >> 5) + lrow) * (IN_F / 2) +
        ((lane >> 4) & 1) * 16;

    // B fragment (packed 8B) read offset for frag j: group (wn>>4)+j
    const int fOff = (wn >> 4) * 512 + lrow * 16 + (kc >> 1) * 256 + (kc & 1) * 8;

    v4i acc[4][8];
#pragma unroll
    for (int i = 0; i < 4; ++i)
#pragma unroll
        for (int j = 0; j < 8; ++j) acc[i][j] = (v4i){0, 0, 0, 0};

    auto STAGE = [&](int buf, int k0) {
        unsigned char* db = sB[buf] + 2 * wave * 1024;
        async_lds16(bBase + (k0 >> 1), db);
        async_lds16(bBase + (size_t)32 * (IN_F / 2) + (k0 >> 1), db + 1024);
    };

#define LOADA(af, k0)                                                   \
    {                                                                   \
        _Pragma("unroll")                                               \
        for (int i = 0; i < 4; ++i)                                     \
            af[i] = *(const v4i*)(aBase + (size_t)i * 16 * IN_F + (k0)); \
    }

    auto COMPUTE = [&](int buf, const v4i* af) {
        const unsigned char* fB = sB[buf] + fOff;
        v2i pk[8];
#pragma unroll
        for (int j = 0; j < 8; ++j)
            pk[j] = *(const v2i*)(fB + j * 512);
#pragma unroll
        for (int j = 0; j < 8; ++j) {
            const unsigned ux = (unsigned)pk[j][0];
            const unsigned uy = (unsigned)pk[j][1];
            v4i bf;
            bf[0] = (int)(ux & 0x0F0F0F0Fu);          // odd cols, lo half
            bf[1] = (int)(uy & 0x0F0F0F0Fu);          // odd cols, hi half
            bf[2] = (int)((ux >> 4) & 0x0F0F0F0Fu);   // even cols, lo half
            bf[3] = (int)((uy >> 4) & 0x0F0F0F0Fu);   // even cols, hi half
#pragma unroll
            for (int i = 0; i < 4; ++i)
                acc[i][j] = __builtin_amdgcn_mfma_i32_16x16x64_i8(
                    af[i], bf, acc[i][j], 0, 0, 0);
        }
    };

    // ---- software pipeline: A prefetch in regs (no barrier), B dbuf LDS ----
    v4i afA[4], afB[4];
    LOADA(afA, 0);
    STAGE(0, 0);
    for (int t = 0; t < 64; t += 2) {
        const int k0 = t * 64;
        // even step: compute {buf0, afA}; prefetch t+1 -> {buf1, afB}
        LOADA(afB, k0 + 64);                         // t+1 <= 63 always
        STAGE(1, k0 + 64);
        asm volatile("s_waitcnt vmcnt(6)" ::: "memory");  // t's 6 ops landed
        __builtin_amdgcn_s_barrier();
        __builtin_amdgcn_sched_barrier(0);
        COMPUTE(0, afA);
        __builtin_amdgcn_sched_barrier(0);
        __builtin_amdgcn_s_barrier();
        // odd step: compute {buf1, afB}; prefetch t+2 -> {buf0, afA}
        if (t + 2 < 64) {
            LOADA(afA, k0 + 128);
            STAGE(0, k0 + 128);
            asm volatile("s_waitcnt vmcnt(6)" ::: "memory");
        } else {
            asm volatile("s_waitcnt vmcnt(0)" ::: "memory");
        }
        __builtin_amdgcn_s_barrier();
        __builtin_amdgcn_sched_barrier(0);
        COMPUTE(1, afB);
        __builtin_amdgcn_sched_barrier(0);
        __builtin_amdgcn_s_barrier();
    }

    // epilogue: true_acc = acc - 8*rowsum[m]  (zero-point for biased nibbles)
    //           out = true_acc * act_scale[m]*wscale[n] + bias[n]
    // C/D mapping: col = lane&15, row = (lane>>4)*4 + reg
    const int col_lane = lane & 15;
    const int row_q    = (lane >> 4) * 4;
    float4 as4[4];
    int4   rs4[4];
#pragma unroll
    for (int i = 0; i < 4; ++i) {
        as4[i] = *(const float4*)(act_scale + m0 + wm + i * 16 + row_q);
        rs4[i] = *(const int4*)(rowsum + m0 + wm + i * 16 + row_q);
    }

#pragma unroll
    for (int j = 0; j < 8; ++j) {
        const int n = n0 + wn + j * 16 + col_lane;
        const float wsn = wscale[n];
        const float bn  = bias[n];
#pragma unroll
        for (int i = 0; i < 4; ++i) {
            const int mb = m0 + wm + i * 16 + row_q;
            float* orow = out + (size_t)mb * OUT_F + n;
            const float* asp = (const float*)&as4[i];
            const int*   rsp = (const int*)&rs4[i];
#pragma unroll
            for (int r = 0; r < 4; ++r)
                orow[(size_t)r * OUT_F] =
                    (float)(acc[i][j][r] - 8 * rsp[r]) * (asp[r] * wsn) + bn;
        }
    }
}

// ---------------------------------------------------------------------------
extern "C" void kernel_launch(void* const* d_in, const int* in_sizes, int n_in,
                              void* d_out, int out_size, void* d_ws, size_t ws_size,
                              hipStream_t stream) {
    const float* x    = (const float*)d_in[0];
    const int*   qw   = (const int*)d_in[1];
    const float* wsc  = (const float*)d_in[2];
    const float* bias = (const float*)d_in[3];
    float* out = (float*)d_out;

    char* ws = (char*)d_ws;
    float*         act_scale = (float*)ws;                          // 64 KB
    int*           rowsum    = (int*)(ws + 65536);                  // 64 KB
    signed char*   qx        = (signed char*)(ws + 131072);         // 64 MB
    unsigned char* w4        = (unsigned char*)(ws + 131072 + (size_t)TOKENS * IN_F); // 8 MB

    act_quant_kernel<<<TOKENS, 256, 0, stream>>>(x, qx, act_scale, rowsum);
    repack_w_kernel<<<(OUT_F * (IN_F / 2) / 16) / 256, 256, 0, stream>>>(qw, w4);
    gemm_i8_kernel<<<(TOKENS / 128) * (OUT_F / 256), 256, 0, stream>>>(
        qx, w4, act_scale, rowsum, wsc, bias, out);
}